// Round 1
// baseline (397.726 us; speedup 1.0000x reference)
//
#include <hip/hip_runtime.h>

#define BATCH 4
#define CCH 256
#define NN 4096
#define CQ 64

typedef __bf16 bf16;
typedef __bf16 bf16x4 __attribute__((ext_vector_type(4)));
typedef __bf16 bf16x8 __attribute__((ext_vector_type(8)));
typedef float f32x4 __attribute__((ext_vector_type(4)));

static __device__ __forceinline__ f32x4 mfma16(bf16x8 a, bf16x8 b, f32x4 c) {
  return __builtin_amdgcn_mfma_f32_16x16x32_bf16(a, b, c, 0, 0, 0);
}

// ---------------- prep: convert weights to bf16 ----------------
// wkvb = [w_qk (64 rows); w_v (256 rows)] as bf16 [320][256]; wtb = w_trans bf16 [256][256]
__global__ __launch_bounds__(256) void prep_kernel(const float* __restrict__ w_qk,
                                                   const float* __restrict__ w_v,
                                                   const float* __restrict__ w_trans,
                                                   bf16* __restrict__ wkvb,
                                                   bf16* __restrict__ wtb) {
  int i = blockIdx.x * 256 + threadIdx.x;
  if (i < 320 * 256) {
    int r = i >> 8, c = i & 255;
    float v = (r < 64) ? w_qk[r * 256 + c] : w_v[(r - 64) * 256 + c];
    wkvb[i] = (bf16)v;
  }
  if (i < 256 * 256) wtb[i] = (bf16)w_trans[i];
}

// ---------------- transpose x: f32 [b][c][n] -> bf16 [b][n][c] ----------------
__global__ __launch_bounds__(256) void transpose_kernel(const float* __restrict__ x,
                                                        bf16* __restrict__ xTb) {
  __shared__ float t[64][65];
  int b = blockIdx.z, c0 = blockIdx.y * 64, n0 = blockIdx.x * 64;
  int tx = threadIdx.x & 63, ty = threadIdx.x >> 6;
  const float* xp = x + ((size_t)b * CCH + c0) * NN + n0;
#pragma unroll
  for (int j = 0; j < 16; ++j) {
    int cl = ty * 16 + j;
    t[tx][cl] = xp[(size_t)cl * NN + tx];
  }
  __syncthreads();
  bf16* op = xTb + ((size_t)b * NN + n0) * CCH + c0;
#pragma unroll
  for (int j = 0; j < 16; ++j) {
    int nl = ty * 16 + j;
    op[(size_t)nl * CCH + tx] = (bf16)t[nl][tx];
  }
}

// ---------------- kv: K = w_qk*x (stored n-major [n][64]), V = w_v*x + b_v ([c][n]) ----------------
// grid (16, 5, B); block 256. chunk 0 -> K rows 0..63; chunks 1..4 -> V rows (chunk-1)*64..
__global__ __launch_bounds__(256) void kv_kernel(const bf16* __restrict__ wkvb,
                                                 const bf16* __restrict__ xTb,
                                                 const float* __restrict__ b_v,
                                                 bf16* __restrict__ Knq,
                                                 bf16* __restrict__ V) {
  int b = blockIdx.z, chunk = blockIdx.y;
  int w = threadIdx.x >> 6, lane = threadIdx.x & 63, lg = lane >> 4, lr = lane & 15;
  int n0 = blockIdx.x * 256 + w * 64;
  int r0 = chunk * 64;
  f32x4 z = {0.f, 0.f, 0.f, 0.f};
  f32x4 acc[4][4];
#pragma unroll
  for (int i = 0; i < 4; ++i)
#pragma unroll
    for (int j = 0; j < 4; ++j) acc[i][j] = z;

  for (int ks = 0; ks < 8; ++ks) {
    bf16x8 af[4], bb[4];
#pragma unroll
    for (int t = 0; t < 4; ++t)
      af[t] = *(const bf16x8*)(wkvb + (size_t)(r0 + 16 * t + lr) * 256 + 32 * ks + 8 * lg);
#pragma unroll
    for (int t = 0; t < 4; ++t)
      bb[t] = *(const bf16x8*)(xTb + ((size_t)b * NN + n0 + 16 * t + lr) * CCH + 32 * ks + 8 * lg);
#pragma unroll
    for (int tc = 0; tc < 4; ++tc)
#pragma unroll
      for (int tn = 0; tn < 4; ++tn) acc[tc][tn] = mfma16(af[tc], bb[tn], acc[tc][tn]);
  }

  if (chunk == 0) {
#pragma unroll
    for (int tn = 0; tn < 4; ++tn) {
      int n = n0 + 16 * tn + lr;
#pragma unroll
      for (int tc = 0; tc < 4; ++tc) {
        bf16x4 kb;
#pragma unroll
        for (int r = 0; r < 4; ++r) kb[r] = (bf16)acc[tc][tn][r];
        *(bf16x4*)(Knq + ((size_t)b * NN + n) * CQ + 16 * tc + lg * 4) = kb;
      }
    }
  } else {
#pragma unroll
    for (int tc = 0; tc < 4; ++tc) {
      int c4 = (chunk - 1) * 64 + 16 * tc + lg * 4;
      f32x4 bv = *(const f32x4*)(b_v + c4);
#pragma unroll
      for (int tn = 0; tn < 4; ++tn) {
        int n = n0 + 16 * tn + lr;
#pragma unroll
        for (int r = 0; r < 4; ++r)
          V[((size_t)b * CCH + c4 + r) * NN + n] = (bf16)(acc[tc][tn][r] + bv[r]);
      }
    }
  }
}

// ---------------- stats: rowmax & 1/rowsum of softmax over S = K^T K ----------------
// grid (N/16, B); block 256 = 4 waves, all share rows [n0, n0+16); wave w takes m-chunks (4j+w)*16
__global__ __launch_bounds__(256) void stats_kernel(const bf16* __restrict__ Knq,
                                                    float* __restrict__ rowmax,
                                                    float* __restrict__ invrs) {
  int b = blockIdx.y, n0 = blockIdx.x * 16;
  int w = threadIdx.x >> 6, lane = threadIdx.x & 63, lg = lane >> 4, lr = lane & 15;
  const bf16* Kb = Knq + (size_t)b * NN * CQ;
  bf16x8 a0 = *(const bf16x8*)(Kb + (size_t)(n0 + lr) * CQ + 8 * lg);
  bf16x8 a1 = *(const bf16x8*)(Kb + (size_t)(n0 + lr) * CQ + 32 + 8 * lg);
  f32x4 z = {0.f, 0.f, 0.f, 0.f};

  float lm[4] = {-1e30f, -1e30f, -1e30f, -1e30f};
  for (int j = 0; j < 64; ++j) {
    int m0 = (j * 4 + w) * 16;
    bf16x8 b0 = *(const bf16x8*)(Kb + (size_t)(m0 + lr) * CQ + 8 * lg);
    bf16x8 b1 = *(const bf16x8*)(Kb + (size_t)(m0 + lr) * CQ + 32 + 8 * lg);
    f32x4 s = mfma16(a0, b0, z);
    s = mfma16(a1, b1, s);
#pragma unroll
    for (int r = 0; r < 4; ++r) lm[r] = fmaxf(lm[r], s[r]);
  }
#pragma unroll
  for (int d = 1; d < 16; d <<= 1)
#pragma unroll
    for (int r = 0; r < 4; ++r) lm[r] = fmaxf(lm[r], __shfl_xor(lm[r], d));

  float ls[4] = {0.f, 0.f, 0.f, 0.f};
  for (int j = 0; j < 64; ++j) {
    int m0 = (j * 4 + w) * 16;
    bf16x8 b0 = *(const bf16x8*)(Kb + (size_t)(m0 + lr) * CQ + 8 * lg);
    bf16x8 b1 = *(const bf16x8*)(Kb + (size_t)(m0 + lr) * CQ + 32 + 8 * lg);
    f32x4 s = mfma16(a0, b0, z);
    s = mfma16(a1, b1, s);
#pragma unroll
    for (int r = 0; r < 4; ++r) ls[r] += __expf(s[r] - lm[r]);
  }
#pragma unroll
  for (int d = 1; d < 16; d <<= 1)
#pragma unroll
    for (int r = 0; r < 4; ++r) ls[r] += __shfl_xor(ls[r], d);

  __shared__ float sm[4][16], ss[4][16];
  if (lr == 0) {
#pragma unroll
    for (int r = 0; r < 4; ++r) {
      sm[w][lg * 4 + r] = lm[r];
      ss[w][lg * 4 + r] = ls[r];
    }
  }
  __syncthreads();
  if (threadIdx.x < 16) {
    float M = sm[0][threadIdx.x];
    for (int ww = 1; ww < 4; ++ww) M = fmaxf(M, sm[ww][threadIdx.x]);
    float S = 0.f;
    for (int ww = 0; ww < 4; ++ww) S += ss[ww][threadIdx.x] * __expf(sm[ww][threadIdx.x] - M);
    rowmax[(size_t)b * NN + n0 + threadIdx.x] = M;
    invrs[(size_t)b * NN + n0 + threadIdx.x] = 1.0f / S;
  }
}

// ---------------- pv: U = V*P, colsum, write D^T = x^T - NF^T (bf16 [n][c]) ----------------
// grid (N/32, B); block 256 = 4 waves. WG owns 32 output columns (m) x all 256 c, loops n.
__global__ __launch_bounds__(256) void pv_kernel(const bf16* __restrict__ Knq,
                                                 const bf16* __restrict__ V,
                                                 const float* __restrict__ rowmax,
                                                 const float* __restrict__ invrs,
                                                 const bf16* __restrict__ xTb,
                                                 bf16* __restrict__ DTb) {
  __shared__ bf16 Plds[32][72];  // P^T tile: [m_local][n_local], pitch 72 keeps b128 reads 16B-aligned
  __shared__ float csl[4][32];
  __shared__ float csv[32];
  int b = blockIdx.y, m0 = blockIdx.x * 32;
  int w = threadIdx.x >> 6, lane = threadIdx.x & 63, lg = lane >> 4, lr = lane & 15;
  const bf16* Kb = Knq + (size_t)b * NN * CQ;
  f32x4 z = {0.f, 0.f, 0.f, 0.f};

  bf16x8 bS[2][2];
#pragma unroll
  for (int tj = 0; tj < 2; ++tj) {
    bS[tj][0] = *(const bf16x8*)(Kb + (size_t)(m0 + 16 * tj + lr) * CQ + 8 * lg);
    bS[tj][1] = *(const bf16x8*)(Kb + (size_t)(m0 + 16 * tj + lr) * CQ + 32 + 8 * lg);
  }

  f32x4 acc[4][2];
#pragma unroll
  for (int i = 0; i < 4; ++i) {
    acc[i][0] = z;
    acc[i][1] = z;
  }
  float cs[2] = {0.f, 0.f};

  for (int n0 = 0; n0 < NN; n0 += 64) {
    int nr = n0 + 16 * w;  // this wave's 16 S-rows
    bf16x8 a0 = *(const bf16x8*)(Kb + (size_t)(nr + lr) * CQ + 8 * lg);
    bf16x8 a1 = *(const bf16x8*)(Kb + (size_t)(nr + lr) * CQ + 32 + 8 * lg);
    f32x4 rm = *(const f32x4*)(rowmax + (size_t)b * NN + nr + lg * 4);
    f32x4 ri = *(const f32x4*)(invrs + (size_t)b * NN + nr + lg * 4);
#pragma unroll
    for (int tj = 0; tj < 2; ++tj) {
      f32x4 s = mfma16(a0, bS[tj][0], z);
      s = mfma16(a1, bS[tj][1], s);
      bf16x4 pb;
#pragma unroll
      for (int r = 0; r < 4; ++r) {
        float p = __expf(s[r] - rm[r]) * ri[r];
        cs[tj] += p;
        pb[r] = (bf16)p;
      }
      *(bf16x4*)&Plds[16 * tj + lr][16 * w + lg * 4] = pb;
    }
    __syncthreads();
#pragma unroll
    for (int ks = 0; ks < 2; ++ks) {
      bf16x8 bp[2];
#pragma unroll
      for (int tj = 0; tj < 2; ++tj)
        bp[tj] = *(const bf16x8*)&Plds[16 * tj + lr][32 * ks + 8 * lg];
#pragma unroll
      for (int tc = 0; tc < 4; ++tc) {
        bf16x8 av = *(const bf16x8*)(V + ((size_t)b * CCH + 64 * w + 16 * tc + lr) * NN + n0 + 32 * ks + 8 * lg);
        acc[tc][0] = mfma16(av, bp[0], acc[tc][0]);
        acc[tc][1] = mfma16(av, bp[1], acc[tc][1]);
      }
    }
    __syncthreads();
  }

  // colsum: reduce per-lane partials across the four 16-lane groups, then across waves
#pragma unroll
  for (int tj = 0; tj < 2; ++tj) {
    cs[tj] += __shfl_xor(cs[tj], 16);
    cs[tj] += __shfl_xor(cs[tj], 32);
  }
  if (lane < 16) {
    csl[w][lane] = cs[0];
    csl[w][16 + lane] = cs[1];
  }
  __syncthreads();
  if (threadIdx.x < 32) {
    float s = csl[0][threadIdx.x] + csl[1][threadIdx.x] + csl[2][threadIdx.x] + csl[3][threadIdx.x];
    csv[threadIdx.x] = 1.0f / (1e-9f + s);
  }
  __syncthreads();

  // epilogue: DT[m][c] = x^T[m][c] - U[c][m]*csv[m]
#pragma unroll
  for (int tj = 0; tj < 2; ++tj) {
    int ml = 16 * tj + lr;
    int m = m0 + ml;
    float ci = csv[ml];
#pragma unroll
    for (int tc = 0; tc < 4; ++tc) {
      int c4 = 64 * w + 16 * tc + lg * 4;
      bf16x4 xv = *(const bf16x4*)(xTb + ((size_t)b * NN + m) * CCH + c4);
      bf16x4 dv;
#pragma unroll
      for (int r = 0; r < 4; ++r) dv[r] = (bf16)((float)xv[r] - acc[tc][tj][r] * ci);
      *(bf16x4*)(DTb + ((size_t)b * NN + m) * CCH + c4) = dv;
    }
  }
}

// ---------------- final: out = ReLU(BN(w_trans * D + b_trans)) ----------------
// grid (N/64, B); block 256 = 4 waves; wave w handles cout rows 64w..64w+63
__global__ __launch_bounds__(256) void final_kernel(const bf16* __restrict__ wtb,
                                                    const bf16* __restrict__ DTb,
                                                    const float* __restrict__ b_trans,
                                                    const float* __restrict__ gamma,
                                                    const float* __restrict__ beta,
                                                    const float* __restrict__ mean,
                                                    const float* __restrict__ var,
                                                    float* __restrict__ out) {
  int b = blockIdx.y;
  int w = threadIdx.x >> 6, lane = threadIdx.x & 63, lg = lane >> 4, lr = lane & 15;
  int n0 = blockIdx.x * 64;
  f32x4 z = {0.f, 0.f, 0.f, 0.f};
  f32x4 acc[4][4];
#pragma unroll
  for (int i = 0; i < 4; ++i)
#pragma unroll
    for (int j = 0; j < 4; ++j) acc[i][j] = z;

  for (int ks = 0; ks < 8; ++ks) {
    bf16x8 a[4], bb[4];
#pragma unroll
    for (int t = 0; t < 4; ++t)
      a[t] = *(const bf16x8*)(wtb + (size_t)(64 * w + 16 * t + lr) * 256 + 32 * ks + 8 * lg);
#pragma unroll
    for (int t = 0; t < 4; ++t)
      bb[t] = *(const bf16x8*)(DTb + ((size_t)b * NN + n0 + 16 * t + lr) * CCH + 32 * ks + 8 * lg);
#pragma unroll
    for (int tc = 0; tc < 4; ++tc)
#pragma unroll
      for (int tn = 0; tn < 4; ++tn) acc[tc][tn] = mfma16(a[tc], bb[tn], acc[tc][tn]);
  }

#pragma unroll
  for (int tc = 0; tc < 4; ++tc) {
    int c4 = 64 * w + 16 * tc + lg * 4;
    f32x4 bt = *(const f32x4*)(b_trans + c4);
    f32x4 gm = *(const f32x4*)(gamma + c4);
    f32x4 be = *(const f32x4*)(beta + c4);
    f32x4 mn = *(const f32x4*)(mean + c4);
    f32x4 vr = *(const f32x4*)(var + c4);
    f32x4 sc, sh;
#pragma unroll
    for (int r = 0; r < 4; ++r) {
      sc[r] = gm[r] * rsqrtf(vr[r] + 1e-5f);
      sh[r] = be[r] - mn[r] * sc[r];
    }
#pragma unroll
    for (int tn = 0; tn < 4; ++tn) {
      int n = n0 + 16 * tn + lr;
#pragma unroll
      for (int r = 0; r < 4; ++r) {
        float y = (acc[tc][tn][r] + bt[r]) * sc[r] + sh[r];
        out[((size_t)b * CCH + c4 + r) * NN + n] = fmaxf(y, 0.0f);
      }
    }
  }
}

extern "C" void kernel_launch(void* const* d_in, const int* in_sizes, int n_in,
                              void* d_out, int out_size, void* d_ws, size_t ws_size,
                              hipStream_t stream) {
  const float* x = (const float*)d_in[0];
  const float* w_qk = (const float*)d_in[1];
  const float* w_v = (const float*)d_in[2];
  const float* b_v = (const float*)d_in[3];
  const float* w_trans = (const float*)d_in[4];
  const float* b_trans = (const float*)d_in[5];
  const float* gamma = (const float*)d_in[6];
  const float* beta = (const float*)d_in[7];
  const float* mean = (const float*)d_in[8];
  const float* var = (const float*)d_in[9];
  float* out = (float*)d_out;

  char* p = (char*)d_ws;
  bf16* wkvb = (bf16*)p; p += (size_t)320 * 256 * 2;
  bf16* wtb = (bf16*)p;  p += (size_t)256 * 256 * 2;
  bf16* xTb = (bf16*)p;  p += (size_t)BATCH * NN * CCH * 2;
  bf16* Knq = (bf16*)p;  p += (size_t)BATCH * NN * CQ * 2;
  bf16* V = (bf16*)p;    p += (size_t)BATCH * CCH * NN * 2;
  float* rowmax = (float*)p; p += (size_t)BATCH * NN * 4;
  float* invrs = (float*)p;  p += (size_t)BATCH * NN * 4;
  bf16* DTb = (bf16*)p;  p += (size_t)BATCH * NN * CCH * 2;

  hipLaunchKernelGGL(prep_kernel, dim3(320), dim3(256), 0, stream, w_qk, w_v, w_trans, wkvb, wtb);
  hipLaunchKernelGGL(transpose_kernel, dim3(NN / 64, CCH / 64, BATCH), dim3(256), 0, stream, x, xTb);
  hipLaunchKernelGGL(kv_kernel, dim3(NN / 256, 5, BATCH), dim3(256), 0, stream, wkvb, xTb, b_v, Knq, V);
  hipLaunchKernelGGL(stats_kernel, dim3(NN / 16, BATCH), dim3(256), 0, stream, Knq, rowmax, invrs);
  hipLaunchKernelGGL(pv_kernel, dim3(NN / 32, BATCH), dim3(256), 0, stream, Knq, V, rowmax, invrs, xTb, DTb);
  hipLaunchKernelGGL(final_kernel, dim3(NN / 64, BATCH), dim3(256), 0, stream, wtb, DTb, b_trans, gamma, beta, mean, var, out);
}

// Round 5
// 295.440 us; speedup vs baseline: 1.3462x; 1.3462x over previous
//
#include <hip/hip_runtime.h>

#define BATCH 4
#define CCH 256
#define NN 4096
#define CQ 64

typedef __bf16 bf16;
typedef __bf16 bf16x4 __attribute__((ext_vector_type(4)));
typedef __bf16 bf16x8 __attribute__((ext_vector_type(8)));
typedef float f32x4 __attribute__((ext_vector_type(4)));

static __device__ __forceinline__ f32x4 mfma16(bf16x8 a, bf16x8 b, f32x4 c) {
  return __builtin_amdgcn_mfma_f32_16x16x32_bf16(a, b, c, 0, 0, 0);
}

// ---------------- prep: convert weights to bf16 (round-1 proven) ----------------
__global__ __launch_bounds__(256) void prep_kernel(const float* __restrict__ w_qk,
                                                   const float* __restrict__ w_v,
                                                   const float* __restrict__ w_trans,
                                                   bf16* __restrict__ wkvb,
                                                   bf16* __restrict__ wtb) {
  int i = blockIdx.x * 256 + threadIdx.x;
  if (i < 320 * 256) {
    int r = i >> 8, c = i & 255;
    float v = (r < 64) ? w_qk[r * 256 + c] : w_v[(r - 64) * 256 + c];
    wkvb[i] = (bf16)v;
  }
  if (i < 256 * 256) wtb[i] = (bf16)w_trans[i];
}

// ---------------- transpose x: f32 [b][c][n] -> bf16 [b][n][c] (round-1 proven) ----------------
__global__ __launch_bounds__(256) void transpose_kernel(const float* __restrict__ x,
                                                        bf16* __restrict__ xTb) {
  __shared__ float t[64][65];
  int b = blockIdx.z, c0 = blockIdx.y * 64, n0 = blockIdx.x * 64;
  int tx = threadIdx.x & 63, ty = threadIdx.x >> 6;
  const float* xp = x + ((size_t)b * CCH + c0) * NN + n0;
#pragma unroll
  for (int j = 0; j < 16; ++j) {
    int cl = ty * 16 + j;
    t[tx][cl] = xp[(size_t)cl * NN + tx];
  }
  __syncthreads();
  bf16* op = xTb + ((size_t)b * NN + n0) * CCH + c0;
#pragma unroll
  for (int j = 0; j < 16; ++j) {
    int nl = ty * 16 + j;
    op[(size_t)nl * CCH + tx] = (bf16)t[nl][tx];
  }
}

// ---------------- kv: K (n-major [n][64]) + sq[n]=|K_n|^2, V = w_v*x + b_v ([c][n]) ----------------
__global__ __launch_bounds__(256) void kv_kernel(const bf16* __restrict__ wkvb,
                                                 const bf16* __restrict__ xTb,
                                                 const float* __restrict__ b_v,
                                                 bf16* __restrict__ Knq,
                                                 bf16* __restrict__ V,
                                                 float* __restrict__ sq) {
  int b = blockIdx.z, chunk = blockIdx.y;
  int w = threadIdx.x >> 6, lane = threadIdx.x & 63, lg = lane >> 4, lr = lane & 15;
  int n0 = blockIdx.x * 256 + w * 64;
  int r0 = chunk * 64;
  f32x4 z = {0.f, 0.f, 0.f, 0.f};
  f32x4 acc[4][4];
#pragma unroll
  for (int i = 0; i < 4; ++i)
#pragma unroll
    for (int j = 0; j < 4; ++j) acc[i][j] = z;

  for (int ks = 0; ks < 8; ++ks) {
    bf16x8 af[4], bb[4];
#pragma unroll
    for (int t = 0; t < 4; ++t)
      af[t] = *(const bf16x8*)(wkvb + (size_t)(r0 + 16 * t + lr) * 256 + 32 * ks + 8 * lg);
#pragma unroll
    for (int t = 0; t < 4; ++t)
      bb[t] = *(const bf16x8*)(xTb + ((size_t)b * NN + n0 + 16 * t + lr) * CCH + 32 * ks + 8 * lg);
#pragma unroll
    for (int tc = 0; tc < 4; ++tc)
#pragma unroll
      for (int tn = 0; tn < 4; ++tn) acc[tc][tn] = mfma16(af[tc], bb[tn], acc[tc][tn]);
  }

  if (chunk == 0) {
    float sqn[4];
#pragma unroll
    for (int tn = 0; tn < 4; ++tn) {
      int n = n0 + 16 * tn + lr;
#pragma unroll
      for (int tc = 0; tc < 4; ++tc) {
        bf16x4 kb;
#pragma unroll
        for (int r = 0; r < 4; ++r) kb[r] = (bf16)acc[tc][tn][r];
        *(bf16x4*)(Knq + ((size_t)b * NN + n) * CQ + 16 * tc + lg * 4) = kb;
      }
      float s = 0.f;
#pragma unroll
      for (int tc = 0; tc < 4; ++tc)
#pragma unroll
        for (int r = 0; r < 4; ++r) s += acc[tc][tn][r] * acc[tc][tn][r];
      s += __shfl_xor(s, 16);
      s += __shfl_xor(s, 32);
      sqn[tn] = s;
    }
    if (lane < 16) {
#pragma unroll
      for (int tn = 0; tn < 4; ++tn)
        sq[(size_t)b * NN + n0 + 16 * tn + lane] = sqn[tn];
    }
  } else {
#pragma unroll
    for (int tc = 0; tc < 4; ++tc) {
      int c4 = (chunk - 1) * 64 + 16 * tc + lg * 4;
      f32x4 bv = *(const f32x4*)(b_v + c4);
#pragma unroll
      for (int tn = 0; tn < 4; ++tn) {
        int n = n0 + 16 * tn + lr;
#pragma unroll
        for (int r = 0; r < 4; ++r)
          V[((size_t)b * CCH + c4 + r) * NN + n] = (bf16)(acc[tc][tn][r] + bv[r]);
      }
    }
  }
}

// ---------------- rnorm: invr[n] = 1 / sum_m exp(S[n][m] - sq[n]) ; single pass ----------------
// grid (NN/64, B); block 256 = 4 waves; wave w owns rows [n0+16w, +16).
__global__ __launch_bounds__(256) void rnorm_kernel(const bf16* __restrict__ Knq,
                                                    const float* __restrict__ sq,
                                                    float* __restrict__ invr) {
  int b = blockIdx.y, n0 = blockIdx.x * 64;
  int w = threadIdx.x >> 6, lane = threadIdx.x & 63, lg = lane >> 4, lr = lane & 15;
  const bf16* Kb = Knq + (size_t)b * NN * CQ;
  int nr = n0 + 16 * w;
  bf16x8 a0 = *(const bf16x8*)(Kb + (size_t)(nr + lr) * CQ + 8 * lg);
  bf16x8 a1 = *(const bf16x8*)(Kb + (size_t)(nr + lr) * CQ + 32 + 8 * lg);
  f32x4 sh = *(const f32x4*)(sq + (size_t)b * NN + nr + lg * 4);
  f32x4 z = {0.f, 0.f, 0.f, 0.f};
  f32x4 ls = z;
  for (int mt = 0; mt < NN; mt += 64) {
#pragma unroll
    for (int j = 0; j < 4; ++j) {
      int m0 = mt + 16 * j;
      bf16x8 b0 = *(const bf16x8*)(Kb + (size_t)(m0 + lr) * CQ + 8 * lg);
      bf16x8 b1 = *(const bf16x8*)(Kb + (size_t)(m0 + lr) * CQ + 32 + 8 * lg);
      f32x4 s = mfma16(a0, b0, z);
      s = mfma16(a1, b1, s);
#pragma unroll
      for (int r = 0; r < 4; ++r) ls[r] += __expf(s[r] - sh[r]);
    }
  }
#pragma unroll
  for (int d = 1; d < 16; d <<= 1)
#pragma unroll
    for (int r = 0; r < 4; ++r) ls[r] += __shfl_xor(ls[r], d);
  if (lr == 0) {
#pragma unroll
    for (int r = 0; r < 4; ++r)
      invr[(size_t)b * NN + nr + lg * 4 + r] = 1.0f / ls[r];
  }
}

// ---------------- pv: m-tile 64, 8 waves, n-step 128; writes DT = xT - NF^T ----------------
// grid (NN/64, B); block 512. Wave w: S-rows n0+16w; PV c-rows [32w, +32).
__global__ __launch_bounds__(512) void pv_kernel(const bf16* __restrict__ Knq,
                                                 const bf16* __restrict__ V,
                                                 const float* __restrict__ sq,
                                                 const float* __restrict__ invr,
                                                 const bf16* __restrict__ xTb,
                                                 bf16* __restrict__ DTb) {
  __shared__ bf16 Plds[64][136];  // P^T tile [m_local][n_local], pitch 136
  __shared__ float csl[8][64];
  __shared__ float csv[64];
  int b = blockIdx.y, m0 = blockIdx.x * 64;
  int w = threadIdx.x >> 6, lane = threadIdx.x & 63, lg = lane >> 4, lr = lane & 15;
  const bf16* Kb = Knq + (size_t)b * NN * CQ;
  const bf16* Vb = V + (size_t)b * CCH * NN;
  f32x4 z = {0.f, 0.f, 0.f, 0.f};

  bf16x8 bS[4][2];
#pragma unroll
  for (int tj = 0; tj < 4; ++tj) {
    bS[tj][0] = *(const bf16x8*)(Kb + (size_t)(m0 + 16 * tj + lr) * CQ + 8 * lg);
    bS[tj][1] = *(const bf16x8*)(Kb + (size_t)(m0 + 16 * tj + lr) * CQ + 32 + 8 * lg);
  }

  f32x4 acc[2][4];  // [tc][tj]
#pragma unroll
  for (int i = 0; i < 2; ++i)
#pragma unroll
    for (int j = 0; j < 4; ++j) acc[i][j] = z;
  float cs[4] = {0.f, 0.f, 0.f, 0.f};

  for (int n0 = 0; n0 < NN; n0 += 128) {
    int nr = n0 + 16 * w;
    bf16x8 a0 = *(const bf16x8*)(Kb + (size_t)(nr + lr) * CQ + 8 * lg);
    bf16x8 a1 = *(const bf16x8*)(Kb + (size_t)(nr + lr) * CQ + 32 + 8 * lg);
    f32x4 sh = *(const f32x4*)(sq + (size_t)b * NN + nr + lg * 4);
    f32x4 ri = *(const f32x4*)(invr + (size_t)b * NN + nr + lg * 4);
#pragma unroll
    for (int tj = 0; tj < 4; ++tj) {
      f32x4 s = mfma16(a0, bS[tj][0], z);
      s = mfma16(a1, bS[tj][1], s);
      bf16x4 pb;
#pragma unroll
      for (int r = 0; r < 4; ++r) {
        float p = __expf(s[r] - sh[r]) * ri[r];
        cs[tj] += p;
        pb[r] = (bf16)p;
      }
      *(bf16x4*)&Plds[16 * tj + lr][16 * w + lg * 4] = pb;
    }
    __syncthreads();
#pragma unroll
    for (int ks = 0; ks < 4; ++ks) {
      bf16x8 bp[4];
#pragma unroll
      for (int tj = 0; tj < 4; ++tj)
        bp[tj] = *(const bf16x8*)&Plds[16 * tj + lr][32 * ks + 8 * lg];
#pragma unroll
      for (int tc = 0; tc < 2; ++tc) {
        bf16x8 av = *(const bf16x8*)(Vb + (size_t)(32 * w + 16 * tc + lr) * NN + n0 + 32 * ks + 8 * lg);
#pragma unroll
        for (int tj = 0; tj < 4; ++tj) acc[tc][tj] = mfma16(av, bp[tj], acc[tc][tj]);
      }
    }
    __syncthreads();
  }

  // column sums: reduce per-lane partials over lg, then across waves
#pragma unroll
  for (int tj = 0; tj < 4; ++tj) {
    cs[tj] += __shfl_xor(cs[tj], 16);
    cs[tj] += __shfl_xor(cs[tj], 32);
  }
  if (lane < 16) {
#pragma unroll
    for (int tj = 0; tj < 4; ++tj) csl[w][16 * tj + lane] = cs[tj];
  }
  __syncthreads();
  if (threadIdx.x < 64) {
    int t = threadIdx.x;
    float s = 0.f;
#pragma unroll
    for (int ww = 0; ww < 8; ++ww) s += csl[ww][t];
    csv[t] = 1.0f / (1e-9f + s);
  }
  __syncthreads();

  // epilogue: DT[m][c] = xT[m][c] - U[c][m]*csv[m]
#pragma unroll
  for (int tj = 0; tj < 4; ++tj) {
    int ml = 16 * tj + lr;
    int m = m0 + ml;
    float ci = csv[ml];
#pragma unroll
    for (int tc = 0; tc < 2; ++tc) {
      int c4 = 32 * w + 16 * tc + lg * 4;
      bf16x4 xv = *(const bf16x4*)(xTb + ((size_t)b * NN + m) * CCH + c4);
      bf16x4 dv;
#pragma unroll
      for (int r = 0; r < 4; ++r) dv[r] = (bf16)((float)xv[r] - acc[tc][tj][r] * ci);
      *(bf16x4*)(DTb + ((size_t)b * NN + m) * CCH + c4) = dv;
    }
  }
}

// ---------------- final: out = ReLU(BN(w_trans * D + b_trans)) (round-1 proven) ----------------
// grid (N/64, B); block 256 = 4 waves; wave w handles cout rows 64w..64w+63
__global__ __launch_bounds__(256) void final_kernel(const bf16* __restrict__ wtb,
                                                    const bf16* __restrict__ DTb,
                                                    const float* __restrict__ b_trans,
                                                    const float* __restrict__ gamma,
                                                    const float* __restrict__ beta,
                                                    const float* __restrict__ mean,
                                                    const float* __restrict__ var,
                                                    float* __restrict__ out) {
  int b = blockIdx.y;
  int w = threadIdx.x >> 6, lane = threadIdx.x & 63, lg = lane >> 4, lr = lane & 15;
  int n0 = blockIdx.x * 64;
  f32x4 z = {0.f, 0.f, 0.f, 0.f};
  f32x4 acc[4][4];
#pragma unroll
  for (int i = 0; i < 4; ++i)
#pragma unroll
    for (int j = 0; j < 4; ++j) acc[i][j] = z;

  for (int ks = 0; ks < 8; ++ks) {
    bf16x8 a[4], bb[4];
#pragma unroll
    for (int t = 0; t < 4; ++t)
      a[t] = *(const bf16x8*)(wtb + (size_t)(64 * w + 16 * t + lr) * 256 + 32 * ks + 8 * lg);
#pragma unroll
    for (int t = 0; t < 4; ++t)
      bb[t] = *(const bf16x8*)(DTb + ((size_t)b * NN + n0 + 16 * t + lr) * CCH + 32 * ks + 8 * lg);
#pragma unroll
    for (int tc = 0; tc < 4; ++tc)
#pragma unroll
      for (int tn = 0; tn < 4; ++tn) acc[tc][tn] = mfma16(a[tc], bb[tn], acc[tc][tn]);
  }

#pragma unroll
  for (int tc = 0; tc < 4; ++tc) {
    int c4 = 64 * w + 16 * tc + lg * 4;
    f32x4 bt = *(const f32x4*)(b_trans + c4);
    f32x4 gm = *(const f32x4*)(gamma + c4);
    f32x4 be = *(const f32x4*)(beta + c4);
    f32x4 mn = *(const f32x4*)(mean + c4);
    f32x4 vr = *(const f32x4*)(var + c4);
    f32x4 sc, shv;
#pragma unroll
    for (int r = 0; r < 4; ++r) {
      sc[r] = gm[r] * rsqrtf(vr[r] + 1e-5f);
      shv[r] = be[r] - mn[r] * sc[r];
    }
#pragma unroll
    for (int tn = 0; tn < 4; ++tn) {
      int n = n0 + 16 * tn + lr;
#pragma unroll
      for (int r = 0; r < 4; ++r) {
        float y = (acc[tc][tn][r] + bt[r]) * sc[r] + shv[r];
        out[((size_t)b * CCH + c4 + r) * NN + n] = fmaxf(y, 0.0f);
      }
    }
  }
}

extern "C" void kernel_launch(void* const* d_in, const int* in_sizes, int n_in,
                              void* d_out, int out_size, void* d_ws, size_t ws_size,
                              hipStream_t stream) {
  const float* x = (const float*)d_in[0];
  const float* w_qk = (const float*)d_in[1];
  const float* w_v = (const float*)d_in[2];
  const float* b_v = (const float*)d_in[3];
  const float* w_trans = (const float*)d_in[4];
  const float* b_trans = (const float*)d_in[5];
  const float* gamma = (const float*)d_in[6];
  const float* beta = (const float*)d_in[7];
  const float* mean = (const float*)d_in[8];
  const float* var = (const float*)d_in[9];
  float* out = (float*)d_out;

  char* p = (char*)d_ws;
  bf16* wkvb = (bf16*)p; p += (size_t)320 * 256 * 2;
  bf16* wtb = (bf16*)p;  p += (size_t)256 * 256 * 2;
  bf16* xTb = (bf16*)p;  p += (size_t)BATCH * NN * CCH * 2;
  bf16* Knq = (bf16*)p;  p += (size_t)BATCH * NN * CQ * 2;
  bf16* V = (bf16*)p;    p += (size_t)BATCH * CCH * NN * 2;
  float* sq = (float*)p;   p += (size_t)BATCH * NN * 4;
  float* invr = (float*)p; p += (size_t)BATCH * NN * 4;
  bf16* DTb = (bf16*)p;  p += (size_t)BATCH * NN * CCH * 2;

  hipLaunchKernelGGL(prep_kernel, dim3(320), dim3(256), 0, stream, w_qk, w_v, w_trans, wkvb, wtb);
  hipLaunchKernelGGL(transpose_kernel, dim3(NN / 64, CCH / 64, BATCH), dim3(256), 0, stream, x, xTb);
  hipLaunchKernelGGL(kv_kernel, dim3(NN / 256, 5, BATCH), dim3(256), 0, stream, wkvb, xTb, b_v, Knq, V, sq);
  hipLaunchKernelGGL(rnorm_kernel, dim3(NN / 64, BATCH), dim3(256), 0, stream, Knq, sq, invr);
  hipLaunchKernelGGL(pv_kernel, dim3(NN / 64, BATCH), dim3(512), 0, stream, Knq, V, sq, invr, xTb, DTb);
  hipLaunchKernelGGL(final_kernel, dim3(NN / 64, BATCH), dim3(256), 0, stream, wtb, DTb, b_trans, gamma, beta, mean, var, out);
}

// Round 6
// 287.647 us; speedup vs baseline: 1.3827x; 1.0271x over previous
//
#include <hip/hip_runtime.h>

#define BATCH 4
#define CCH 256
#define NN 4096
#define CQ 64

typedef __bf16 bf16;
typedef __bf16 bf16x4 __attribute__((ext_vector_type(4)));
typedef __bf16 bf16x8 __attribute__((ext_vector_type(8)));
typedef float f32x4 __attribute__((ext_vector_type(4)));

static __device__ __forceinline__ f32x4 mfma16(bf16x8 a, bf16x8 b, f32x4 c) {
  return __builtin_amdgcn_mfma_f32_16x16x32_bf16(a, b, c, 0, 0, 0);
}

// ---------------- prep: convert weights to bf16 ----------------
__global__ __launch_bounds__(256) void prep_kernel(const float* __restrict__ w_qk,
                                                   const float* __restrict__ w_v,
                                                   const float* __restrict__ w_trans,
                                                   bf16* __restrict__ wkvb,
                                                   bf16* __restrict__ wtb) {
  int i = blockIdx.x * 256 + threadIdx.x;
  if (i < 320 * 256) {
    int r = i >> 8, c = i & 255;
    float v = (r < 64) ? w_qk[r * 256 + c] : w_v[(r - 64) * 256 + c];
    wkvb[i] = (bf16)v;
  }
  if (i < 256 * 256) wtb[i] = (bf16)w_trans[i];
}

// ---------------- transpose x: f32 [b][c][n] -> bf16 [b][n][c] ----------------
__global__ __launch_bounds__(256) void transpose_kernel(const float* __restrict__ x,
                                                        bf16* __restrict__ xTb) {
  __shared__ float t[64][65];
  int b = blockIdx.z, c0 = blockIdx.y * 64, n0 = blockIdx.x * 64;
  int tx = threadIdx.x & 63, ty = threadIdx.x >> 6;
  const float* xp = x + ((size_t)b * CCH + c0) * NN + n0;
#pragma unroll
  for (int j = 0; j < 16; ++j) {
    int cl = ty * 16 + j;
    t[tx][cl] = xp[(size_t)cl * NN + tx];
  }
  __syncthreads();
  bf16* op = xTb + ((size_t)b * NN + n0) * CCH + c0;
#pragma unroll
  for (int j = 0; j < 16; ++j) {
    int nl = ty * 16 + j;
    op[(size_t)nl * CCH + tx] = (bf16)t[nl][tx];
  }
}

// ---------------- kv: K (n-major [n][64]) + sq[n]=|K_n|^2, V = w_v*x + b_v ([c][n]) ----------------
__global__ __launch_bounds__(256) void kv_kernel(const bf16* __restrict__ wkvb,
                                                 const bf16* __restrict__ xTb,
                                                 const float* __restrict__ b_v,
                                                 bf16* __restrict__ Knq,
                                                 bf16* __restrict__ V,
                                                 float* __restrict__ sq) {
  int b = blockIdx.z, chunk = blockIdx.y;
  int w = threadIdx.x >> 6, lane = threadIdx.x & 63, lg = lane >> 4, lr = lane & 15;
  int n0 = blockIdx.x * 256 + w * 64;
  int r0 = chunk * 64;
  f32x4 z = {0.f, 0.f, 0.f, 0.f};
  f32x4 acc[4][4];
#pragma unroll
  for (int i = 0; i < 4; ++i)
#pragma unroll
    for (int j = 0; j < 4; ++j) acc[i][j] = z;

  for (int ks = 0; ks < 8; ++ks) {
    bf16x8 af[4], bb[4];
#pragma unroll
    for (int t = 0; t < 4; ++t)
      af[t] = *(const bf16x8*)(wkvb + (size_t)(r0 + 16 * t + lr) * 256 + 32 * ks + 8 * lg);
#pragma unroll
    for (int t = 0; t < 4; ++t)
      bb[t] = *(const bf16x8*)(xTb + ((size_t)b * NN + n0 + 16 * t + lr) * CCH + 32 * ks + 8 * lg);
#pragma unroll
    for (int tc = 0; tc < 4; ++tc)
#pragma unroll
      for (int tn = 0; tn < 4; ++tn) acc[tc][tn] = mfma16(af[tc], bb[tn], acc[tc][tn]);
  }

  if (chunk == 0) {
    float sqn[4];
#pragma unroll
    for (int tn = 0; tn < 4; ++tn) {
      int n = n0 + 16 * tn + lr;
#pragma unroll
      for (int tc = 0; tc < 4; ++tc) {
        bf16x4 kb;
#pragma unroll
        for (int r = 0; r < 4; ++r) kb[r] = (bf16)acc[tc][tn][r];
        *(bf16x4*)(Knq + ((size_t)b * NN + n) * CQ + 16 * tc + lg * 4) = kb;
      }
      float s = 0.f;
#pragma unroll
      for (int tc = 0; tc < 4; ++tc)
#pragma unroll
        for (int r = 0; r < 4; ++r) s += acc[tc][tn][r] * acc[tc][tn][r];
      s += __shfl_xor(s, 16);
      s += __shfl_xor(s, 32);
      sqn[tn] = s;
    }
    if (lane < 16) {
#pragma unroll
      for (int tn = 0; tn < 4; ++tn)
        sq[(size_t)b * NN + n0 + 16 * tn + lane] = sqn[tn];
    }
  } else {
#pragma unroll
    for (int tc = 0; tc < 4; ++tc) {
      int c4 = (chunk - 1) * 64 + 16 * tc + lg * 4;
      f32x4 bv = *(const f32x4*)(b_v + c4);
#pragma unroll
      for (int tn = 0; tn < 4; ++tn) {
        int n = n0 + 16 * tn + lr;
#pragma unroll
        for (int r = 0; r < 4; ++r)
          V[((size_t)b * CCH + c4 + r) * NN + n] = (bf16)(acc[tc][tn][r] + bv[r]);
      }
    }
  }
}

// ---------------- rnorm: invr[n] = 1 / sum_m exp(S[n][m] - sq[n]) ----------------
// grid (NN/64, B); block 512 = 8 waves; wave w: n-subtile (w&3), m-half (w>>2).
__global__ __launch_bounds__(512) void rnorm_kernel(const bf16* __restrict__ Knq,
                                                    const float* __restrict__ sq,
                                                    float* __restrict__ invr) {
  __shared__ float lsl[8][16];
  int b = blockIdx.y, n0 = blockIdx.x * 64;
  int w = threadIdx.x >> 6, lane = threadIdx.x & 63, lg = lane >> 4, lr = lane & 15;
  int sn = w & 3, mh = w >> 2;
  const bf16* Kb = Knq + (size_t)b * NN * CQ;
  int nr = n0 + 16 * sn;
  bf16x8 a0 = *(const bf16x8*)(Kb + (size_t)(nr + lr) * CQ + 8 * lg);
  bf16x8 a1 = *(const bf16x8*)(Kb + (size_t)(nr + lr) * CQ + 32 + 8 * lg);
  f32x4 sh = *(const f32x4*)(sq + (size_t)b * NN + nr + lg * 4);
  f32x4 z = {0.f, 0.f, 0.f, 0.f};
  f32x4 ls = z;
  for (int mt = mh * (NN / 2); mt < (mh + 1) * (NN / 2); mt += 64) {
#pragma unroll
    for (int j = 0; j < 4; ++j) {
      int m0 = mt + 16 * j;
      bf16x8 b0 = *(const bf16x8*)(Kb + (size_t)(m0 + lr) * CQ + 8 * lg);
      bf16x8 b1 = *(const bf16x8*)(Kb + (size_t)(m0 + lr) * CQ + 32 + 8 * lg);
      f32x4 s = mfma16(a0, b0, z);
      s = mfma16(a1, b1, s);
#pragma unroll
      for (int r = 0; r < 4; ++r) ls[r] += __expf(s[r] - sh[r]);
    }
  }
#pragma unroll
  for (int d = 1; d < 16; d <<= 1)
#pragma unroll
    for (int r = 0; r < 4; ++r) ls[r] += __shfl_xor(ls[r], d);
  if (lr == 0) {
#pragma unroll
    for (int r = 0; r < 4; ++r) lsl[w][lg * 4 + r] = ls[r];
  }
  __syncthreads();
  if (threadIdx.x < 64) {
    int t = threadIdx.x;
    float S = lsl[t >> 4][t & 15] + lsl[(t >> 4) + 4][t & 15];
    invr[(size_t)b * NN + n0 + t] = 1.0f / S;
  }
}

// ---------------- pv: single-barrier pipelined, swizzled P, XCD-batch-local ----------------
// grid (NN/64, B); block 512. Wave w: S-rows n-window+16w; PV c-rows [32w, +32).
#define SWZ(row, colb) ((colb) ^ (((row)&7) << 4))
__global__ __launch_bounds__(512) void pv_kernel(const bf16* __restrict__ Knq,
                                                 const bf16* __restrict__ V,
                                                 const float* __restrict__ sq,
                                                 const float* __restrict__ invr,
                                                 const bf16* __restrict__ xTb,
                                                 bf16* __restrict__ DTb) {
  __shared__ bf16 P2[2][64][128];  // [buf][m_local][n_local], swizzled cols
  __shared__ float csl[8][64];
  __shared__ float csv[64];
  // XCD remap: each XCD (blk%8) serves one batch so V(2MB)+K(.5MB) stay L2-local
  int lin = blockIdx.y * (NN / 64) + blockIdx.x;  // 0..255
  int xcd = lin & 7, slot = lin >> 3;
  int b = xcd >> 1;
  int m0 = (((xcd & 1) << 5) | slot) * 64;
  int w = threadIdx.x >> 6, lane = threadIdx.x & 63, lg = lane >> 4, lr = lane & 15;
  const bf16* Kb = Knq + (size_t)b * NN * CQ;
  const bf16* Vb = V + (size_t)b * CCH * NN;
  f32x4 z = {0.f, 0.f, 0.f, 0.f};

  bf16x8 bS[4][2];
#pragma unroll
  for (int tj = 0; tj < 4; ++tj) {
    bS[tj][0] = *(const bf16x8*)(Kb + (size_t)(m0 + 16 * tj + lr) * CQ + 8 * lg);
    bS[tj][1] = *(const bf16x8*)(Kb + (size_t)(m0 + 16 * tj + lr) * CQ + 32 + 8 * lg);
  }

  f32x4 acc[2][4];  // [tc][tj]
#pragma unroll
  for (int i = 0; i < 2; ++i)
#pragma unroll
    for (int j = 0; j < 4; ++j) acc[i][j] = z;
  float cs[4] = {0.f, 0.f, 0.f, 0.f};

#define S_PHASE(STEP, BUF)                                                          \
  {                                                                                 \
    int nr_ = (STEP) * 128 + 16 * w;                                                \
    bf16x8 a0_ = *(const bf16x8*)(Kb + (size_t)(nr_ + lr) * CQ + 8 * lg);           \
    bf16x8 a1_ = *(const bf16x8*)(Kb + (size_t)(nr_ + lr) * CQ + 32 + 8 * lg);      \
    f32x4 sh_ = *(const f32x4*)(sq + (size_t)b * NN + nr_ + lg * 4);                \
    f32x4 ri_ = *(const f32x4*)(invr + (size_t)b * NN + nr_ + lg * 4);              \
    _Pragma("unroll") for (int tj = 0; tj < 4; ++tj) {                              \
      f32x4 s4 = mfma16(a0_, bS[tj][0], z);                                         \
      s4 = mfma16(a1_, bS[tj][1], s4);                                              \
      bf16x4 pb;                                                                    \
      _Pragma("unroll") for (int r = 0; r < 4; ++r) {                               \
        float p_ = __expf(s4[r] - sh_[r]) * ri_[r];                                 \
        cs[tj] += p_;                                                               \
        pb[r] = (bf16)p_;                                                           \
      }                                                                             \
      *(bf16x4*)((char*)&P2[BUF][16 * tj + lr][0] + SWZ(lr, 2 * (16 * w + 4 * lg))) = pb; \
    }                                                                               \
  }

  S_PHASE(0, 0);
  __syncthreads();

  for (int s = 0; s < NN / 128; ++s) {
    int cur = s & 1;
    int ns = s * 128;
    // early: P-tile ds_reads + V preloads for this step
    bf16x8 bp[4][4];
#pragma unroll
    for (int ks = 0; ks < 4; ++ks)
#pragma unroll
      for (int tj = 0; tj < 4; ++tj)
        bp[ks][tj] = *(const bf16x8*)((char*)&P2[cur][16 * tj + lr][0] +
                                      SWZ(16 * tj + lr, 2 * (32 * ks + 8 * lg)));
    bf16x8 av[4][2];
#pragma unroll
    for (int ks = 0; ks < 4; ++ks)
#pragma unroll
      for (int tc = 0; tc < 2; ++tc)
        av[ks][tc] = *(const bf16x8*)(Vb + (size_t)(32 * w + 16 * tc + lr) * NN + ns + 32 * ks + 8 * lg);
    // overlap: next step's S while PV consumes current
    if (s + 1 < NN / 128) S_PHASE(s + 1, cur ^ 1);
#pragma unroll
    for (int ks = 0; ks < 4; ++ks)
#pragma unroll
      for (int tc = 0; tc < 2; ++tc)
#pragma unroll
        for (int tj = 0; tj < 4; ++tj) acc[tc][tj] = mfma16(av[ks][tc], bp[ks][tj], acc[tc][tj]);
    __syncthreads();
  }

  // column sums: reduce per-lane partials over lg, then across waves
#pragma unroll
  for (int tj = 0; tj < 4; ++tj) {
    cs[tj] += __shfl_xor(cs[tj], 16);
    cs[tj] += __shfl_xor(cs[tj], 32);
  }
  if (lane < 16) {
#pragma unroll
    for (int tj = 0; tj < 4; ++tj) csl[w][16 * tj + lane] = cs[tj];
  }
  __syncthreads();
  if (threadIdx.x < 64) {
    int t = threadIdx.x;
    float s = 0.f;
#pragma unroll
    for (int ww = 0; ww < 8; ++ww) s += csl[ww][t];
    csv[t] = 1.0f / (1e-9f + s);
  }
  __syncthreads();

  // epilogue: DT[m][c] = xT[m][c] - U[c][m]*csv[m]
#pragma unroll
  for (int tj = 0; tj < 4; ++tj) {
    int ml = 16 * tj + lr;
    int m = m0 + ml;
    float ci = csv[ml];
#pragma unroll
    for (int tc = 0; tc < 2; ++tc) {
      int c4 = 32 * w + 16 * tc + lg * 4;
      bf16x4 xv = *(const bf16x4*)(xTb + ((size_t)b * NN + m) * CCH + c4);
      bf16x4 dv;
#pragma unroll
      for (int r = 0; r < 4; ++r) dv[r] = (bf16)((float)xv[r] - acc[tc][tj][r] * ci);
      *(bf16x4*)(DTb + ((size_t)b * NN + m) * CCH + c4) = dv;
    }
  }
}

// ---------------- final: out = ReLU(BN(w_trans * D + b_trans)) ----------------
// grid (N/64, B); block 256 = 4 waves; wave w handles cout rows 64w..64w+63
__global__ __launch_bounds__(256) void final_kernel(const bf16* __restrict__ wtb,
                                                    const bf16* __restrict__ DTb,
                                                    const float* __restrict__ b_trans,
                                                    const float* __restrict__ gamma,
                                                    const float* __restrict__ beta,
                                                    const float* __restrict__ mean,
                                                    const float* __restrict__ var,
                                                    float* __restrict__ out) {
  int b = blockIdx.y;
  int w = threadIdx.x >> 6, lane = threadIdx.x & 63, lg = lane >> 4, lr = lane & 15;
  int n0 = blockIdx.x * 64;
  f32x4 z = {0.f, 0.f, 0.f, 0.f};
  f32x4 acc[4][4];
#pragma unroll
  for (int i = 0; i < 4; ++i)
#pragma unroll
    for (int j = 0; j < 4; ++j) acc[i][j] = z;

  for (int ks = 0; ks < 8; ++ks) {
    bf16x8 a[4], bb[4];
#pragma unroll
    for (int t = 0; t < 4; ++t)
      a[t] = *(const bf16x8*)(wtb + (size_t)(64 * w + 16 * t + lr) * 256 + 32 * ks + 8 * lg);
#pragma unroll
    for (int t = 0; t < 4; ++t)
      bb[t] = *(const bf16x8*)(DTb + ((size_t)b * NN + n0 + 16 * t + lr) * CCH + 32 * ks + 8 * lg);
#pragma unroll
    for (int tc = 0; tc < 4; ++tc)
#pragma unroll
      for (int tn = 0; tn < 4; ++tn) acc[tc][tn] = mfma16(a[tc], bb[tn], acc[tc][tn]);
  }

#pragma unroll
  for (int tc = 0; tc < 4; ++tc) {
    int c4 = 64 * w + 16 * tc + lg * 4;
    f32x4 bt = *(const f32x4*)(b_trans + c4);
    f32x4 gm = *(const f32x4*)(gamma + c4);
    f32x4 be = *(const f32x4*)(beta + c4);
    f32x4 mn = *(const f32x4*)(mean + c4);
    f32x4 vr = *(const f32x4*)(var + c4);
    f32x4 sc, shv;
#pragma unroll
    for (int r = 0; r < 4; ++r) {
      sc[r] = gm[r] * rsqrtf(vr[r] + 1e-5f);
      shv[r] = be[r] - mn[r] * sc[r];
    }
#pragma unroll
    for (int tn = 0; tn < 4; ++tn) {
      int n = n0 + 16 * tn + lr;
#pragma unroll
      for (int r = 0; r < 4; ++r) {
        float y = (acc[tc][tn][r] + bt[r]) * sc[r] + shv[r];
        out[((size_t)b * CCH + c4 + r) * NN + n] = fmaxf(y, 0.0f);
      }
    }
  }
}

extern "C" void kernel_launch(void* const* d_in, const int* in_sizes, int n_in,
                              void* d_out, int out_size, void* d_ws, size_t ws_size,
                              hipStream_t stream) {
  const float* x = (const float*)d_in[0];
  const float* w_qk = (const float*)d_in[1];
  const float* w_v = (const float*)d_in[2];
  const float* b_v = (const float*)d_in[3];
  const float* w_trans = (const float*)d_in[4];
  const float* b_trans = (const float*)d_in[5];
  const float* gamma = (const float*)d_in[6];
  const float* beta = (const float*)d_in[7];
  const float* mean = (const float*)d_in[8];
  const float* var = (const float*)d_in[9];
  float* out = (float*)d_out;

  char* p = (char*)d_ws;
  bf16* wkvb = (bf16*)p; p += (size_t)320 * 256 * 2;
  bf16* wtb = (bf16*)p;  p += (size_t)256 * 256 * 2;
  bf16* xTb = (bf16*)p;  p += (size_t)BATCH * NN * CCH * 2;
  bf16* Knq = (bf16*)p;  p += (size_t)BATCH * NN * CQ * 2;
  bf16* V = (bf16*)p;    p += (size_t)BATCH * CCH * NN * 2;
  float* sq = (float*)p;   p += (size_t)BATCH * NN * 4;
  float* invr = (float*)p; p += (size_t)BATCH * NN * 4;
  bf16* DTb = (bf16*)p;  p += (size_t)BATCH * NN * CCH * 2;

  hipLaunchKernelGGL(prep_kernel, dim3(320), dim3(256), 0, stream, w_qk, w_v, w_trans, wkvb, wtb);
  hipLaunchKernelGGL(transpose_kernel, dim3(NN / 64, CCH / 64, BATCH), dim3(256), 0, stream, x, xTb);
  hipLaunchKernelGGL(kv_kernel, dim3(NN / 256, 5, BATCH), dim3(256), 0, stream, wkvb, xTb, b_v, Knq, V, sq);
  hipLaunchKernelGGL(rnorm_kernel, dim3(NN / 64, BATCH), dim3(512), 0, stream, Knq, sq, invr);
  hipLaunchKernelGGL(pv_kernel, dim3(NN / 64, BATCH), dim3(512), 0, stream, Knq, V, sq, invr, xTb, DTb);
  hipLaunchKernelGGL(final_kernel, dim3(NN / 64, BATCH), dim3(256), 0, stream, wtb, DTb, b_trans, gamma, beta, mean, var, out);
}